// Round 8
// baseline (239.769 us; speedup 1.0000x reference)
//
#include <hip/hip_runtime.h>

#define ROW_T   8192
#define CHUNK   256               // elems per wave-chunk
#define CPR     (ROW_T / CHUNK)   // 32 chunks per row
#define THREADS 256
#define WPB     4                 // waves (=chunks) per block
#define EPSV    1e-4f

typedef float fvec4 __attribute__((ext_vector_type(4)));
typedef float fvec2 __attribute__((ext_vector_type(2)));

// ---- DPP scan helpers (pure VALU) ----
template<int CTRL, int RM>
__device__ __forceinline__ float dpp_add(float v) {
    const int p = __builtin_amdgcn_update_dpp(0, __float_as_int(v), CTRL, RM, 0xf, true);
    return v + __int_as_float(p);
}
__device__ __forceinline__ float scan64(float v) {   // 64-lane inclusive scan
    v = dpp_add<0x111, 0xf>(v);   // row_shr:1
    v = dpp_add<0x112, 0xf>(v);   // row_shr:2
    v = dpp_add<0x114, 0xf>(v);   // row_shr:4
    v = dpp_add<0x118, 0xf>(v);   // row_shr:8
    v = dpp_add<0x142, 0xa>(v);   // row_bcast:15 -> rows 1,3
    v = dpp_add<0x143, 0xc>(v);   // row_bcast:31 -> rows 2,3
    return v;
}
__device__ __forceinline__ float scan32(float v) {   // 32-lane inclusive (per half)
    v = dpp_add<0x111, 0xf>(v);
    v = dpp_add<0x112, 0xf>(v);
    v = dpp_add<0x114, 0xf>(v);
    v = dpp_add<0x118, 0xf>(v);
    v = dpp_add<0x142, 0xa>(v);   // completes 32-lane scan within each half
    return v;
}

// ======== pass 1: per-chunk (sum, sumsq) -> ws. Pure streaming read. ========
__global__ __launch_bounds__(THREADS, 8)
void sums_kernel(const float* __restrict__ x, fvec2* __restrict__ ws) {
    const int lane = threadIdx.x & 63;
    const int wid  = threadIdx.x >> 6;
    const long long g = (long long)blockIdx.x * WPB + wid;   // global chunk id

    const fvec4 c = *reinterpret_cast<const fvec4*>(x + g * CHUNK + lane * 4);
    float s  = (c.x + c.y) + (c.z + c.w);
    float ss = fmaf(c.x, c.x, fmaf(c.y, c.y, fmaf(c.z, c.z, c.w * c.w)));
    const float ts  = scan64(s);    // lane 63 = chunk total
    const float tss = scan64(ss);
    if (lane == 63) ws[g] = fvec2{ts, tss};
}

// ======== pass 2: independent per-chunk normalize. Structurally a copy. ========
__global__ __launch_bounds__(THREADS, 8)
void norm_kernel(const float* __restrict__ x, const fvec2* __restrict__ ws,
                 float* __restrict__ out) {
    const int lane = threadIdx.x & 63;
    const int wid  = threadIdx.x >> 6;
    const long long g = (long long)blockIdx.x * WPB + wid;   // global chunk id
    const int cidx = (int)(g & (CPR - 1));                   // chunk index within row
    const long long rowc0 = g - cidx;                        // row's first chunk id

    // chunk data (1KB dense per wave)
    const fvec4 c = *reinterpret_cast<const fvec4*>(x + g * CHUNK + lane * 4);

    // row's 32 chunk totals: lane i (and i+32) holds chunk i's (s,ss); scan across chunks
    const fvec2 t = ws[rowc0 + (lane & 31)];
    const float ps  = scan32(t.x);
    const float pss = scan32(t.y);
    // exclusive row-prefix at this chunk's start (wave-uniform readlane)
    float S0 = 0.f, SS0 = 0.f;
    if (cidx > 0) {
        S0  = __int_as_float(__builtin_amdgcn_readlane(__float_as_int(ps),  cidx - 1));
        SS0 = __int_as_float(__builtin_amdgcn_readlane(__float_as_int(pss), cidx - 1));
    }

    // within-chunk scan
    float s  = (c.x + c.y) + (c.z + c.w);
    float ss = fmaf(c.x, c.x, fmaf(c.y, c.y, fmaf(c.z, c.z, c.w * c.w)));
    const float is  = scan64(s);
    const float iss = scan64(ss);

    float S  = S0  + (is  - s);     // exclusive prefix at this lane's first elem
    float SS = SS0 + (iss - ss);

    const int e0 = cidx * CHUNK + lane * 4;   // position within the row
    fvec4 o;
#define CN_STEP(v, idx, dst) {                                            \
        S += (v); SS = fmaf((v), (v), SS);                                \
        const float inv  = __builtin_amdgcn_rcpf((float)(e0 + (idx) + 1));\
        const float mean = S * inv;                                       \
        const float var  = fmaf(SS, inv, -(mean * mean));                 \
        (dst) = ((v) - mean) * __builtin_amdgcn_rsqf(var + EPSV);         \
    }
    CN_STEP(c.x, 0, o.x)
    CN_STEP(c.y, 1, o.y)
    CN_STEP(c.z, 2, o.z)
    CN_STEP(c.w, 3, o.w)
#undef CN_STEP

    *reinterpret_cast<fvec4*>(out + g * CHUNK + lane * 4) = o;
}

extern "C" void kernel_launch(void* const* d_in, const int* in_sizes, int n_in,
                              void* d_out, int out_size, void* d_ws, size_t ws_size,
                              hipStream_t stream) {
    const float* x = (const float*)d_in[0];
    float* out = (float*)d_out;
    fvec2* ws = (fvec2*)d_ws;                     // 131072 chunks x 8B = 1 MB
    const int rows   = out_size / ROW_T;          // 4096
    const int blocks = rows * CPR / WPB;          // 32768

    sums_kernel<<<blocks, THREADS, 0, stream>>>(x, ws);
    norm_kernel<<<blocks, THREADS, 0, stream>>>(x, ws, out);
}